// Round 1
// 733.159 us; speedup vs baseline: 1.0490x; 1.0490x over previous
//
#include <hip/hip_runtime.h>
#include <math.h>

#define S 512
#define W 64
#define MODES 16
#define PAIRS 130816  // 512*511/2
#define INV_SQRT_N 0.04419417382415922f  // 1/sqrt(512)
#define TWO_PI_OVER_N 0.012271846303085130f  // 2*pi/512

// ---------------- fc0: h[b,c,t] = x[b,t,0]*w[0,c] + x[b,t,1]*w[1,c] + bias[c]
__global__ __launch_bounds__(256) void k_fc0(const float* __restrict__ x,
                                             const float* __restrict__ w,
                                             const float* __restrict__ bias,
                                             float* __restrict__ h) {
    int b = blockIdx.x >> 6, c = blockIdx.x & 63;
    int tid = threadIdx.x;
    float w0 = w[c], w1 = w[64 + c], bb = bias[c];
    for (int t = tid; t < S; t += 256) {
        float x0 = x[(b * S + t) * 2];
        float x1 = x[(b * S + t) * 2 + 1];
        h[(b * W + c) * S + t] = x0 * w0 + x1 * w1 + bb;
    }
}

// ---------------- rfft (ortho), first 16 modes only. block=(b,c), 256 thr.
__global__ __launch_bounds__(256) void k_fft(const float* __restrict__ h,
                                             float* __restrict__ Xf) {
    int b = blockIdx.x >> 6, ch = blockIdx.x & 63;
    int tid = threadIdx.x;  // t = tid and tid+256
    const float* hp = h + (b * W + ch) * S;
    float v0 = hp[tid], v1 = hp[tid + 256];
    float re[MODES], im[MODES];
#pragma unroll
    for (int m = 0; m < MODES; ++m) {
        float sn, cs;
        sincosf(TWO_PI_OVER_N * (float)(m * tid), &sn, &cs);
        float a = (m & 1) ? (v0 - v1) : (v0 + v1);  // e^{-i pi m} = (-1)^m
        re[m] = a * cs;
        im[m] = -a * sn;
    }
    __shared__ float part[4][32];
    int lane = tid & 63, wv = tid >> 6;
#pragma unroll
    for (int m = 0; m < MODES; ++m) {
        float r = re[m], ii = im[m];
        for (int off = 32; off; off >>= 1) {
            r += __shfl_down(r, off);
            ii += __shfl_down(ii, off);
        }
        if (lane == 0) { part[wv][2 * m] = r; part[wv][2 * m + 1] = ii; }
    }
    __syncthreads();
    if (tid < 32) {
        float s = part[0][tid] + part[1][tid] + part[2][tid] + part[3][tid];
        Xf[(b * W + ch) * 32 + tid] = s * INV_SQRT_N;
    }
}

// ---------------- complex channel mix: Y[b,o,m] = sum_i Xf[b,i,m]*wm[i,o,m]
__global__ __launch_bounds__(256) void k_mix(const float* __restrict__ Xf,
                                             const float* __restrict__ specw,
                                             float* __restrict__ Y, int l) {
    int b = blockIdx.x >> 6, o = blockIdx.x & 63;
    int tid = threadIdx.x, m = tid & 15, ip = tid >> 4;
    __shared__ float Xs[2048];
    for (int idx = tid; idx < 2048; idx += 256) Xs[idx] = Xf[b * 2048 + idx];
    __syncthreads();
    float ar = 0.f, ai = 0.f;
#pragma unroll
    for (int q = 0; q < 4; ++q) {
        int i = ip * 4 + q;
        const float* wp = specw + (size_t)(((l * W + i) * W + o) * MODES + m) * 2;
        float wr = wp[0], wi = wp[1];
        float xr = Xs[i * 32 + 2 * m], xi = Xs[i * 32 + 2 * m + 1];
        ar += xr * wr - xi * wi;
        ai += xr * wi + xi * wr;
    }
    __shared__ float redr[16][17], redi[16][17];
    redr[ip][m] = ar; redi[ip][m] = ai;
    __syncthreads();
    if (tid < 16) {
        float sr = 0.f, si = 0.f;
        for (int p = 0; p < 16; ++p) { sr += redr[p][tid]; si += redi[p][tid]; }
        Y[(b * W + o) * 32 + 2 * tid] = sr;
        Y[(b * W + o) * 32 + 2 * tid + 1] = si;
    }
}

// ---------------- fused irfft (ortho, 16 modes) + pointwise conv.
// 256 blocks = b(2) x 128 t-tiles of 4. thread: o = tid&63, t = t0 + (tid>>6).
__global__ __launch_bounds__(256) void k_ac(const float* __restrict__ Y,
                                            const float* __restrict__ h,
                                            const float* __restrict__ convw,
                                            const float* __restrict__ convb,
                                            float* __restrict__ aT,
                                            float* __restrict__ pT,
                                            unsigned* __restrict__ vmax, int l) {
    int blk = blockIdx.x;
    int b = blk >> 7, t0 = (blk & 127) * 4;
    int tid = threadIdx.x;
    int o = tid & 63, tg = tid >> 6;
    if (blk == 0 && tid < 2) vmax[tid] = 0u;  // zero v_r_max for this layer
    __shared__ float hs[64 * 5];
    if (tid < 256) {
        int r = tid >> 2, t = tid & 3;
        hs[r * 5 + t] = h[(b * W + r) * S + t0 + t];
    }
    // Y modes for this thread's channel: 32 consecutive floats, own 128B segment.
    float yr[MODES], yi[MODES];
    const float4* yp = (const float4*)(Y + b * 2048 + o * 32);
#pragma unroll
    for (int q = 0; q < 8; ++q) {
        float4 y4 = yp[q];
        yr[2 * q] = y4.x; yi[2 * q] = y4.y;
        yr[2 * q + 1] = y4.z; yi[2 * q + 1] = y4.w;
    }
    int t = t0 + tg;
    float acc = yr[0];
#pragma unroll
    for (int m = 1; m < MODES; ++m) {
        float sn, cs;
        sincosf(TWO_PI_OVER_N * (float)(m * t), &sn, &cs);
        acc += 2.0f * (yr[m] * cs - yi[m] * sn);
    }
    aT[((size_t)b * S + t) * W + o] = acc * INV_SQRT_N;
    // ---- conv: own weight row, 64 consecutive floats via float4
    __syncthreads();
    float pacc = convb[l * W + o];
    const float4* wp = (const float4*)(convw + l * 4096 + o * 64);
#pragma unroll
    for (int i4 = 0; i4 < 16; ++i4) {
        float4 w4 = wp[i4];
        pacc = fmaf(w4.x, hs[(4 * i4 + 0) * 5 + tg], pacc);
        pacc = fmaf(w4.y, hs[(4 * i4 + 1) * 5 + tg], pacc);
        pacc = fmaf(w4.z, hs[(4 * i4 + 2) * 5 + tg], pacc);
        pacc = fmaf(w4.w, hs[(4 * i4 + 3) * 5 + tg], pacc);
    }
    pT[((size_t)b * S + t) * W + o] = pacc;
}

// ---------------- pairwise: v_r[b,j,i], u_x[b,j,i]=exp(-x_r), atomicMax v_r_max
__global__ __launch_bounds__(256) void k_pair(const float* __restrict__ pT,
                                              const float* __restrict__ aT,
                                              float* __restrict__ vr,
                                              float* __restrict__ uxm,
                                              unsigned* __restrict__ vmax) {
    int blk = blockIdx.x;
    int b = blk >> 8;
    int rest = blk & 255;
    int i0 = (rest & 15) * 32, j0 = (rest >> 4) * 32;
    int tid = threadIdx.x;
    int tx = tid & 15, ty = tid >> 4;
    __shared__ float Pi[64 * 33], Pj[64 * 33], Vi[64 * 33], Vj[64 * 33];
    for (int idx = tid; idx < 2048; idx += 256) {
        int k = idx >> 6, c = idx & 63;
        Pi[c * 33 + k] = pT[(b * S + i0 + k) * W + c];
        Pj[c * 33 + k] = pT[(b * S + j0 + k) * W + c];
        Vi[c * 33 + k] = aT[(b * S + i0 + k) * W + c];
        Vj[c * 33 + k] = aT[(b * S + j0 + k) * W + c];
    }
    __syncthreads();
    float ax[2][2] = {{0.f, 0.f}, {0.f, 0.f}};
    float av[2][2] = {{0.f, 0.f}, {0.f, 0.f}};
    for (int c = 0; c < W; ++c) {
        float pi0 = Pi[c * 33 + 2 * tx], pi1 = Pi[c * 33 + 2 * tx + 1];
        float pj0 = Pj[c * 33 + 2 * ty], pj1 = Pj[c * 33 + 2 * ty + 1];
        float vi0 = Vi[c * 33 + 2 * tx], vi1 = Vi[c * 33 + 2 * tx + 1];
        float vj0 = Vj[c * 33 + 2 * ty], vj1 = Vj[c * 33 + 2 * ty + 1];
        float d;
        d = pi0 - pj0; ax[0][0] = fmaf(d, d, ax[0][0]);
        d = pi1 - pj0; ax[1][0] = fmaf(d, d, ax[1][0]);
        d = pi0 - pj1; ax[0][1] = fmaf(d, d, ax[0][1]);
        d = pi1 - pj1; ax[1][1] = fmaf(d, d, ax[1][1]);
        d = vi0 - vj0; av[0][0] = fmaf(d, d, av[0][0]);
        d = vi1 - vj0; av[1][0] = fmaf(d, d, av[1][0]);
        d = vi0 - vj1; av[0][1] = fmaf(d, d, av[0][1]);
        d = vi1 - vj1; av[1][1] = fmaf(d, d, av[1][1]);
    }
    float mx = 0.f;
#pragma unroll
    for (int jj = 0; jj < 2; ++jj) {
#pragma unroll
        for (int ii = 0; ii < 2; ++ii) {
            int i = i0 + 2 * tx + ii, j = j0 + 2 * ty + jj;
            float xr = sqrtf(ax[ii][jj]);
            float vv = sqrtf(av[ii][jj]);
            vr[((size_t)b * S + j) * S + i] = vv;
            uxm[((size_t)b * S + j) * S + i] = expf(-xr);
            mx = fmaxf(mx, vv);
        }
    }
    for (int off = 32; off; off >>= 1) mx = fmaxf(mx, __shfl_xor(mx, off));
    if ((tid & 63) == 0) atomicMax(&vmax[b], __float_as_uint(mx));
}

// ---------------- mask: per row j -> wpair (contiguous upper segment), A, partner sums, Tg=0
__global__ __launch_bounds__(256) void k_mask(const float* __restrict__ vr,
                                              const float* __restrict__ uxm,
                                              const unsigned* __restrict__ vmaxu,
                                              const float* __restrict__ aT,
                                              const float* __restrict__ pT,
                                              float* __restrict__ wpair,
                                              float* __restrict__ sv,
                                              float* __restrict__ sx,
                                              int* __restrict__ Acnt,
                                              float* __restrict__ Tg) {
    int b = blockIdx.x >> 9, j = blockIdx.x & 511;
    int tid = threadIdx.x, lane = tid & 63, wv = tid >> 6;
    __shared__ float wrow[S];
    __shared__ float SV[4][64], SX[4][64];
    __shared__ int cnt4[4];
    const float* vrp = vr + ((size_t)b * S + j) * S;
    const float* uxp = uxm + ((size_t)b * S + j) * S;
    float vmax = __uint_as_float(vmaxu[b]);
    int mycnt = 0;
    for (int i = tid; i < S; i += 256) {
        float v = vrp[i], u = uxp[i];
        bool act = (v / vmax) * u > 0.1f;
        wrow[i] = act ? v : 0.f;
        mycnt += act ? 1 : 0;
    }
    for (int o = 32; o; o >>= 1) mycnt += __shfl_down(mycnt, o);
    if (lane == 0) cnt4[wv] = mycnt;
    __syncthreads();
    int A = cnt4[0] + cnt4[1] + cnt4[2] + cnt4[3];
    if (tid == 0) Acnt[b * S + j] = A;
    if (tid < 64) Tg[((size_t)b * S + j) * W + tid] = 0.f;
    size_t tri = (size_t)j * 511 - (((size_t)j * (j - 1)) >> 1);
    for (int i = j + 1 + tid; i < S; i += 256)
        wpair[(size_t)b * PAIRS + tri + (i - j - 1)] = wrow[i];
    // partner sums: lanes over channels, wave-uniform skip of inactive rows.
    float svp = 0.f, sxp = 0.f;
    const float* aTb = aT + (size_t)b * S * W;
    const float* pTb = pT + (size_t)b * S * W;
    for (int k = 0; k < 128; ++k) {
        int i = wv * 128 + k;
        if (wrow[i] != 0.f) {  // wave-uniform (i uniform across lanes)
            svp += aTb[i * W + lane];
            sxp += pTb[i * W + lane];
        }
    }
    SV[wv][lane] = svp; SX[wv][lane] = sxp;
    __syncthreads();
    if (tid < 64) {
        sv[((size_t)b * S + j) * W + tid] = SV[0][tid] + SV[1][tid] + SV[2][tid] + SV[3][tid];
        sx[((size_t)b * S + j) * W + tid] = SX[0][tid] + SX[1][tid] + SX[2][tid] + SX[3][tid];
    }
}

// ---------------- proj: single coalesced sweep of R, both signs.
// grid (36 upper 64x64 tiles, 8 channel groups, 2 b), 256 thr.
__global__ __launch_bounds__(256) void k_proj2(const float* __restrict__ wpair,
                                               const float* __restrict__ vecs,
                                               float* __restrict__ Tg, int l) {
    int tile = blockIdx.x, cg = blockIdx.y, b = blockIdx.z;
    int ti = 0, rem = tile;
    while (rem >= 8 - ti) { rem -= 8 - ti; ++ti; }
    int tj = ti + rem;
    int i0 = ti * 64, j0 = tj * 64;
    int tid = threadIdx.x, lane = tid & 63, wv = tid >> 6;
    __shared__ float Tjs[4][64][9];
    __shared__ float Tis[64][9];
    for (int k2 = tid; k2 < 4 * 64 * 9; k2 += 256) ((float*)Tjs)[k2] = 0.f;
    for (int k2 = tid; k2 < 64 * 9; k2 += 256) ((float*)Tis)[k2] = 0.f;
    __syncthreads();
    const float* wb = wpair + (size_t)b * PAIRS;
    const float* Rb = vecs + (size_t)((l * 2 + b) * W + cg * 8) * PAIRS;
    float accj[8] = {0.f, 0.f, 0.f, 0.f, 0.f, 0.f, 0.f, 0.f};
    int gj = j0 + lane;
    for (int s = 0; s < 16; ++s) {
        int li = wv + 4 * s;
        int gi = i0 + li;
        int pbase = gi * 511 - ((gi * (gi - 1)) >> 1) + (j0 - gi - 1);
        bool valid = gj > gi;
        int idx = valid ? (pbase + lane) : 0;
        float w = wb[idx];
        if (!valid) w = 0.f;
        if (__ballot(w != 0.f) == 0ull) continue;
        float part[8];
#pragma unroll
        for (int cc = 0; cc < 8; ++cc) {
            float r = Rb[(size_t)cc * PAIRS + idx];
            float p = w * r;
            accj[cc] += p;
            part[cc] = p;
        }
#pragma unroll
        for (int cc = 0; cc < 8; ++cc) {
            float p = part[cc];
            for (int o = 32; o; o >>= 1) p += __shfl_xor(p, o);
            if (lane == 0) Tis[li][cc] = p;
        }
    }
#pragma unroll
    for (int cc = 0; cc < 8; ++cc) Tjs[wv][lane][cc] = accj[cc];
    __syncthreads();
    for (int k2 = tid; k2 < 512; k2 += 256) {
        int r = k2 >> 3, cc = k2 & 7;
        float sj = Tjs[0][r][cc] + Tjs[1][r][cc] + Tjs[2][r][cc] + Tjs[3][r][cc];
        if (sj != 0.f)
            atomicAdd(&Tg[((size_t)b * S + j0 + r) * W + cg * 8 + cc], sj);
        float si = Tis[r][cc];
        if (si != 0.f)
            atomicAdd(&Tg[((size_t)b * S + i0 + r) * W + cg * 8 + cc], -si);
    }
}

// ---------------- finalize: vnew/xnew per (b,j,c); at l==3 fuse the MLP head.
__global__ __launch_bounds__(256) void k_fin(const float* __restrict__ aT,
                                             const float* __restrict__ pT,
                                             const float* __restrict__ sv,
                                             const float* __restrict__ sx,
                                             const int* __restrict__ Acnt,
                                             const float* __restrict__ Tg,
                                             float* __restrict__ h_std,
                                             const float* __restrict__ fc1w,
                                             const float* __restrict__ fc1b,
                                             const float* __restrict__ fc2w,
                                             const float* __restrict__ fc2b,
                                             float* __restrict__ out,
                                             int do_relu, int do_head) {
    int wv = threadIdx.x >> 6;
    int g = blockIdx.x * 4 + wv;  // global row 0..1023
    int b = g >> 9, j = g & 511;
    int c = threadIdx.x & 63;
    size_t row = ((size_t)b * S + j) * W;
    float A = (float)Acnt[b * S + j];
    float vj = aT[row + c], xj = pT[row + c];
    float vnew = vj + 0.5f * (A * vj - sv[row + c]) + Tg[row + c];
    float accx = 0.5f * (A * xj + sx[row + c]);
    float xnew = (xj + accx) / (A + 1.0f) + vnew;
    if (do_relu) xnew = fmaxf(xnew, 0.0f);
    if (!do_head) {
        h_std[((size_t)b * W + c) * S + j] = xnew;
        return;
    }
    // head: out[b,j] = relu(h @ fc1 + b1) @ fc2 + b2, row held across this wave.
    __shared__ float hsh[4][64];
    hsh[wv][c] = xnew;
    __syncthreads();
    float a0 = fc1b[c], a1 = fc1b[c + 64];
    for (int cc = 0; cc < W; ++cc) {
        float hv = hsh[wv][cc];
        a0 = fmaf(hv, fc1w[cc * 128 + c], a0);
        a1 = fmaf(hv, fc1w[cc * 128 + c + 64], a1);
    }
    a0 = fmaxf(a0, 0.f); a1 = fmaxf(a1, 0.f);
    float p = a0 * fc2w[c] + a1 * fc2w[c + 64];
    for (int off = 32; off; off >>= 1) p += __shfl_down(p, off);
    if (c == 0) out[b * S + j] = p + fc2b[0];
}

extern "C" void kernel_launch(void* const* d_in, const int* in_sizes, int n_in,
                              void* d_out, int out_size, void* d_ws, size_t ws_size,
                              hipStream_t stream) {
    const float* x = (const float*)d_in[0];
    const float* vecs = (const float*)d_in[2];
    const float* fc0w = (const float*)d_in[3];
    const float* fc0b = (const float*)d_in[4];
    const float* specw = (const float*)d_in[5];
    const float* convw = (const float*)d_in[6];
    const float* convb = (const float*)d_in[7];
    const float* fc1w = (const float*)d_in[8];
    const float* fc1b = (const float*)d_in[9];
    const float* fc2w = (const float*)d_in[10];
    const float* fc2b = (const float*)d_in[11];
    float* out = (float*)d_out;

    char* ws = (char*)d_ws;
    unsigned* vmax = (unsigned*)ws;                   // 2 x u32 (float bits)
    float* h_std = (float*)(ws + 256);                // 2*64*512
    float* hT = h_std + 65536;                        // (slot kept; unused)
    float* aT = hT + 65536;
    float* pT = aT + 65536;
    float* Xf = pT + 65536;                           // 2*64*32
    float* Yb = Xf + 4096;
    float* vrbuf = Yb + 4096;                         // 2*512*512
    float* uxbuf = vrbuf + 524288;                    // 2*512*512
    float* Tg = uxbuf + 524288;                       // 2*512*64
    float* svb = Tg + 65536;                          // 2*512*64
    float* sxb = svb + 65536;                         // 2*512*64
    int* Acnt = (int*)(sxb + 65536);                  // 2*512
    float* wpair = (float*)(Acnt + 1024);             // 2*PAIRS
    (void)hT;

    k_fc0<<<128, 256, 0, stream>>>(x, fc0w, fc0b, h_std);
    for (int l = 0; l < 4; ++l) {
        k_fft<<<128, 256, 0, stream>>>(h_std, Xf);
        k_mix<<<128, 256, 0, stream>>>(Xf, specw, Yb, l);
        k_ac<<<256, 256, 0, stream>>>(Yb, h_std, convw, convb, aT, pT, vmax, l);
        k_pair<<<512, 256, 0, stream>>>(pT, aT, vrbuf, uxbuf, vmax);
        k_mask<<<1024, 256, 0, stream>>>(vrbuf, uxbuf, vmax, aT, pT,
                                         wpair, svb, sxb, Acnt, Tg);
        k_proj2<<<dim3(36, 8, 2), 256, 0, stream>>>(wpair, vecs, Tg, l);
        k_fin<<<256, 256, 0, stream>>>(aT, pT, svb, sxb, Acnt, Tg,
                                       h_std, fc1w, fc1b, fc2w, fc2b, out,
                                       (l < 3) ? 1 : 0, (l == 3) ? 1 : 0);
    }
}

// Round 2
// 655.882 us; speedup vs baseline: 1.1726x; 1.1178x over previous
//
#include <hip/hip_runtime.h>
#include <math.h>

#define S 512
#define W 64
#define MODES 16
#define PAIRS 130816  // 512*511/2
#define INV_SQRT_N 0.04419417382415922f  // 1/sqrt(512)
#define TWO_PI_OVER_N 0.012271846303085130f  // 2*pi/512

// ---------------- rfft (ortho), first 16 modes only. block=(b,c), 256 thr.
// first!=0: layer-0 input is fc0(x) computed on the fly (h never materialized).
__global__ __launch_bounds__(256) void k_fft(const float* __restrict__ h,
                                             const float* __restrict__ x,
                                             const float* __restrict__ fc0w,
                                             const float* __restrict__ fc0b,
                                             float* __restrict__ Xf, int first) {
    int b = blockIdx.x >> 6, ch = blockIdx.x & 63;
    int tid = threadIdx.x;  // t = tid and tid+256
    float v0, v1;
    if (first) {
        float w0 = fc0w[ch], w1 = fc0w[64 + ch], bb = fc0b[ch];
        const float* xb = x + (size_t)b * S * 2;
        v0 = xb[2 * tid] * w0 + xb[2 * tid + 1] * w1 + bb;
        v1 = xb[2 * (tid + 256)] * w0 + xb[2 * (tid + 256) + 1] * w1 + bb;
    } else {
        const float* hp = h + (b * W + ch) * S;
        v0 = hp[tid]; v1 = hp[tid + 256];
    }
    float re[MODES], im[MODES];
#pragma unroll
    for (int m = 0; m < MODES; ++m) {
        float sn, cs;
        sincosf(TWO_PI_OVER_N * (float)(m * tid), &sn, &cs);
        float a = (m & 1) ? (v0 - v1) : (v0 + v1);  // e^{-i pi m} = (-1)^m
        re[m] = a * cs;
        im[m] = -a * sn;
    }
    __shared__ float part[4][32];
    int lane = tid & 63, wv = tid >> 6;
#pragma unroll
    for (int m = 0; m < MODES; ++m) {
        float r = re[m], ii = im[m];
        for (int off = 32; off; off >>= 1) {
            r += __shfl_down(r, off);
            ii += __shfl_down(ii, off);
        }
        if (lane == 0) { part[wv][2 * m] = r; part[wv][2 * m + 1] = ii; }
    }
    __syncthreads();
    if (tid < 32) {
        float s = part[0][tid] + part[1][tid] + part[2][tid] + part[3][tid];
        Xf[(b * W + ch) * 32 + tid] = s * INV_SQRT_N;
    }
}

// ---------------- complex channel mix: Y[b,o,m] = sum_i Xf[b,i,m]*wm[i,o,m]
__global__ __launch_bounds__(256) void k_mix(const float* __restrict__ Xf,
                                             const float* __restrict__ specw,
                                             float* __restrict__ Y, int l) {
    int b = blockIdx.x >> 6, o = blockIdx.x & 63;
    int tid = threadIdx.x, m = tid & 15, ip = tid >> 4;
    __shared__ float Xs[2048];
    for (int idx = tid; idx < 2048; idx += 256) Xs[idx] = Xf[b * 2048 + idx];
    __syncthreads();
    float ar = 0.f, ai = 0.f;
#pragma unroll
    for (int q = 0; q < 4; ++q) {
        int i = ip * 4 + q;
        const float* wp = specw + (size_t)(((l * W + i) * W + o) * MODES + m) * 2;
        float wr = wp[0], wi = wp[1];
        float xr = Xs[i * 32 + 2 * m], xi = Xs[i * 32 + 2 * m + 1];
        ar += xr * wr - xi * wi;
        ai += xr * wi + xi * wr;
    }
    __shared__ float redr[16][17], redi[16][17];
    redr[ip][m] = ar; redi[ip][m] = ai;
    __syncthreads();
    if (tid < 16) {
        float sr = 0.f, si = 0.f;
        for (int p = 0; p < 16; ++p) { sr += redr[p][tid]; si += redi[p][tid]; }
        Y[(b * W + o) * 32 + 2 * tid] = sr;
        Y[(b * W + o) * 32 + 2 * tid + 1] = si;
    }
}

// ---------------- fused irfft (ortho, 16 modes) + pointwise conv.
// 256 blocks = b(2) x 128 t-tiles of 4. thread: o = tid&63, t = t0 + (tid>>6).
__global__ __launch_bounds__(256) void k_ac(const float* __restrict__ Y,
                                            const float* __restrict__ h,
                                            const float* __restrict__ x,
                                            const float* __restrict__ fc0w,
                                            const float* __restrict__ fc0b,
                                            const float* __restrict__ convw,
                                            const float* __restrict__ convb,
                                            float* __restrict__ aT,
                                            float* __restrict__ pT,
                                            unsigned* __restrict__ vmax,
                                            int l, int first) {
    int blk = blockIdx.x;
    int b = blk >> 7, t0 = (blk & 127) * 4;
    int tid = threadIdx.x;
    int o = tid & 63, tg = tid >> 6;
    if (blk == 0 && tid < 2) vmax[tid] = 0u;  // zero v_r_max for this layer
    __shared__ float hs[64 * 5];
    {
        int r = tid >> 2, t = tid & 3;
        if (first) {
            const float* xb = x + ((size_t)b * S + t0 + t) * 2;
            hs[r * 5 + t] = xb[0] * fc0w[r] + xb[1] * fc0w[64 + r] + fc0b[r];
        } else {
            hs[r * 5 + t] = h[(b * W + r) * S + t0 + t];
        }
    }
    // Y modes for this thread's channel: 32 consecutive floats, own 128B segment.
    float yr[MODES], yi[MODES];
    const float4* yp = (const float4*)(Y + b * 2048 + o * 32);
#pragma unroll
    for (int q = 0; q < 8; ++q) {
        float4 y4 = yp[q];
        yr[2 * q] = y4.x; yi[2 * q] = y4.y;
        yr[2 * q + 1] = y4.z; yi[2 * q + 1] = y4.w;
    }
    int t = t0 + tg;
    float acc = yr[0];
#pragma unroll
    for (int m = 1; m < MODES; ++m) {
        float sn, cs;
        sincosf(TWO_PI_OVER_N * (float)(m * t), &sn, &cs);
        acc += 2.0f * (yr[m] * cs - yi[m] * sn);
    }
    aT[((size_t)b * S + t) * W + o] = acc * INV_SQRT_N;
    // ---- conv: own weight row, 64 consecutive floats via float4
    __syncthreads();
    float pacc = convb[l * W + o];
    const float4* wp = (const float4*)(convw + l * 4096 + o * 64);
#pragma unroll
    for (int i4 = 0; i4 < 16; ++i4) {
        float4 w4 = wp[i4];
        pacc = fmaf(w4.x, hs[(4 * i4 + 0) * 5 + tg], pacc);
        pacc = fmaf(w4.y, hs[(4 * i4 + 1) * 5 + tg], pacc);
        pacc = fmaf(w4.z, hs[(4 * i4 + 2) * 5 + tg], pacc);
        pacc = fmaf(w4.w, hs[(4 * i4 + 3) * 5 + tg], pacc);
    }
    pT[((size_t)b * S + t) * W + o] = pacc;
}

// ---------------- pairwise: v_r[b,j,i], u_x[b,j,i]=exp(-x_r), atomicMax v_r_max
__global__ __launch_bounds__(256) void k_pair(const float* __restrict__ pT,
                                              const float* __restrict__ aT,
                                              float* __restrict__ vr,
                                              float* __restrict__ uxm,
                                              unsigned* __restrict__ vmax) {
    int blk = blockIdx.x;
    int b = blk >> 8;
    int rest = blk & 255;
    int i0 = (rest & 15) * 32, j0 = (rest >> 4) * 32;
    int tid = threadIdx.x;
    int tx = tid & 15, ty = tid >> 4;
    __shared__ float Pi[64 * 33], Pj[64 * 33], Vi[64 * 33], Vj[64 * 33];
    for (int idx = tid; idx < 2048; idx += 256) {
        int k = idx >> 6, c = idx & 63;
        Pi[c * 33 + k] = pT[(b * S + i0 + k) * W + c];
        Pj[c * 33 + k] = pT[(b * S + j0 + k) * W + c];
        Vi[c * 33 + k] = aT[(b * S + i0 + k) * W + c];
        Vj[c * 33 + k] = aT[(b * S + j0 + k) * W + c];
    }
    __syncthreads();
    float ax[2][2] = {{0.f, 0.f}, {0.f, 0.f}};
    float av[2][2] = {{0.f, 0.f}, {0.f, 0.f}};
    for (int c = 0; c < W; ++c) {
        float pi0 = Pi[c * 33 + 2 * tx], pi1 = Pi[c * 33 + 2 * tx + 1];
        float pj0 = Pj[c * 33 + 2 * ty], pj1 = Pj[c * 33 + 2 * ty + 1];
        float vi0 = Vi[c * 33 + 2 * tx], vi1 = Vi[c * 33 + 2 * tx + 1];
        float vj0 = Vj[c * 33 + 2 * ty], vj1 = Vj[c * 33 + 2 * ty + 1];
        float d;
        d = pi0 - pj0; ax[0][0] = fmaf(d, d, ax[0][0]);
        d = pi1 - pj0; ax[1][0] = fmaf(d, d, ax[1][0]);
        d = pi0 - pj1; ax[0][1] = fmaf(d, d, ax[0][1]);
        d = pi1 - pj1; ax[1][1] = fmaf(d, d, ax[1][1]);
        d = vi0 - vj0; av[0][0] = fmaf(d, d, av[0][0]);
        d = vi1 - vj0; av[1][0] = fmaf(d, d, av[1][0]);
        d = vi0 - vj1; av[0][1] = fmaf(d, d, av[0][1]);
        d = vi1 - vj1; av[1][1] = fmaf(d, d, av[1][1]);
    }
    float mx = 0.f;
#pragma unroll
    for (int jj = 0; jj < 2; ++jj) {
#pragma unroll
        for (int ii = 0; ii < 2; ++ii) {
            int i = i0 + 2 * tx + ii, j = j0 + 2 * ty + jj;
            float xr = sqrtf(ax[ii][jj]);
            float vv = sqrtf(av[ii][jj]);
            vr[((size_t)b * S + j) * S + i] = vv;
            uxm[((size_t)b * S + j) * S + i] = expf(-xr);
            mx = fmaxf(mx, vv);
        }
    }
    __shared__ float mxs[4];
    for (int off = 32; off; off >>= 1) mx = fmaxf(mx, __shfl_xor(mx, off));
    if ((tid & 63) == 0) mxs[tid >> 6] = mx;
    __syncthreads();
    if (tid == 0) {
        float m = fmaxf(fmaxf(mxs[0], mxs[1]), fmaxf(mxs[2], mxs[3]));
        atomicMax(&vmax[b], __float_as_uint(m));
    }
}

// ---------------- fused mask + per-row projection + finalize (+ head at l==3).
// Row-q formulation: T[q,c] = sum_{p<q,act} w*R[c,pair(p,q)] - sum_{p>q,act} w*R[c,pair(q,p)]
// No wpair buffer, no Tg atomics. Grid 1024 = (b, q), 256 thr, lane = channel.
__global__ __launch_bounds__(256) void k_mpf(const float* __restrict__ vr,
                                             const float* __restrict__ uxm,
                                             const unsigned* __restrict__ vmaxu,
                                             const float* __restrict__ aT,
                                             const float* __restrict__ pT,
                                             const float* __restrict__ vecs,
                                             float* __restrict__ h_std,
                                             const float* __restrict__ fc1w,
                                             const float* __restrict__ fc1b,
                                             const float* __restrict__ fc2w,
                                             const float* __restrict__ fc2b,
                                             float* __restrict__ out,
                                             int l, int do_relu, int do_head) {
    int b = blockIdx.x >> 9, q = blockIdx.x & 511;
    int tid = threadIdx.x, lane = tid & 63, wv = tid >> 6;
    __shared__ float wrow[S];
    __shared__ float SV[4][64], SX[4][64], TP[4][64];
    __shared__ float hrow[64];
    __shared__ int cnt4[4];
    const float* vrp = vr + ((size_t)b * S + q) * S;
    const float* uxp = uxm + ((size_t)b * S + q) * S;
    float vmax = __uint_as_float(vmaxu[b]);
    int mycnt = 0;
    for (int i = tid; i < S; i += 256) {
        float v = vrp[i], u = uxp[i];
        bool act = (v / vmax) * u > 0.1f;
        wrow[i] = act ? v : 0.f;
        mycnt += act ? 1 : 0;
    }
    for (int o = 32; o; o >>= 1) mycnt += __shfl_down(mycnt, o);
    if (lane == 0) cnt4[wv] = mycnt;
    __syncthreads();
    float A = (float)(cnt4[0] + cnt4[1] + cnt4[2] + cnt4[3]);
    // gated sweep: wave wv handles p in [wv*128, wv*128+128), ascending (deterministic)
    float svp = 0.f, sxp = 0.f, tp = 0.f;
    const float* aTb = aT + (size_t)b * S * W;
    const float* pTb = pT + (size_t)b * S * W;
    const float* Rb = vecs + (size_t)((l * 2 + b) * W + lane) * PAIRS;
    int triq = q * 511 - ((q * (q - 1)) >> 1);
    for (int k = 0; k < 128; ++k) {
        int p = wv * 128 + k;
        float w = wrow[p];
        if (w != 0.f) {  // wave-uniform branch
            svp += aTb[p * W + lane];
            sxp += pTb[p * W + lane];
            int idx; float sgn;
            if (p < q) { idx = p * 511 - ((p * (p - 1)) >> 1) + (q - p - 1); sgn = 1.f; }
            else       { idx = triq + (p - q - 1); sgn = -1.f; }
            tp = fmaf(sgn * w, Rb[idx], tp);
        }
    }
    SV[wv][lane] = svp; SX[wv][lane] = sxp; TP[wv][lane] = tp;
    __syncthreads();
    if (wv == 0) {
        float sv = SV[0][lane] + SV[1][lane] + SV[2][lane] + SV[3][lane];
        float sx = SX[0][lane] + SX[1][lane] + SX[2][lane] + SX[3][lane];
        float T  = TP[0][lane] + TP[1][lane] + TP[2][lane] + TP[3][lane];
        float vj = aTb[q * W + lane], xj = pTb[q * W + lane];
        float vnew = vj + 0.5f * (A * vj - sv) + T;
        float accx = 0.5f * (A * xj + sx);
        float xnew = (xj + accx) / (A + 1.0f) + vnew;
        if (do_relu) xnew = fmaxf(xnew, 0.0f);
        if (!do_head) h_std[((size_t)b * W + lane) * S + q] = xnew;
        else hrow[lane] = xnew;
    }
    if (do_head) {
        __syncthreads();
        if (wv == 0) {
            float a0 = fc1b[lane], a1 = fc1b[lane + 64];
            for (int cc = 0; cc < W; ++cc) {
                float hv = hrow[cc];
                a0 = fmaf(hv, fc1w[cc * 128 + lane], a0);
                a1 = fmaf(hv, fc1w[cc * 128 + lane + 64], a1);
            }
            a0 = fmaxf(a0, 0.f); a1 = fmaxf(a1, 0.f);
            float p = a0 * fc2w[lane] + a1 * fc2w[lane + 64];
            for (int off = 32; off; off >>= 1) p += __shfl_down(p, off);
            if (lane == 0) out[b * S + q] = p + fc2b[0];
        }
    }
}

extern "C" void kernel_launch(void* const* d_in, const int* in_sizes, int n_in,
                              void* d_out, int out_size, void* d_ws, size_t ws_size,
                              hipStream_t stream) {
    const float* x = (const float*)d_in[0];
    const float* vecs = (const float*)d_in[2];
    const float* fc0w = (const float*)d_in[3];
    const float* fc0b = (const float*)d_in[4];
    const float* specw = (const float*)d_in[5];
    const float* convw = (const float*)d_in[6];
    const float* convb = (const float*)d_in[7];
    const float* fc1w = (const float*)d_in[8];
    const float* fc1b = (const float*)d_in[9];
    const float* fc2w = (const float*)d_in[10];
    const float* fc2b = (const float*)d_in[11];
    float* out = (float*)d_out;

    char* ws = (char*)d_ws;
    unsigned* vmax = (unsigned*)ws;                   // 2 x u32 (float bits)
    float* h_std = (float*)(ws + 256);                // 2*64*512
    float* aT = h_std + 65536;                        // 2*512*64
    float* pT = aT + 65536;                           // 2*512*64
    float* Xf = pT + 65536;                           // 2*64*32
    float* Yb = Xf + 4096;                            // 2*64*32
    float* vrbuf = Yb + 4096;                         // 2*512*512
    float* uxbuf = vrbuf + 524288;                    // 2*512*512

    for (int l = 0; l < 4; ++l) {
        int first = (l == 0) ? 1 : 0;
        k_fft<<<128, 256, 0, stream>>>(h_std, x, fc0w, fc0b, Xf, first);
        k_mix<<<128, 256, 0, stream>>>(Xf, specw, Yb, l);
        k_ac<<<256, 256, 0, stream>>>(Yb, h_std, x, fc0w, fc0b, convw, convb,
                                      aT, pT, vmax, l, first);
        k_pair<<<512, 256, 0, stream>>>(pT, aT, vrbuf, uxbuf, vmax);
        k_mpf<<<1024, 256, 0, stream>>>(vrbuf, uxbuf, vmax, aT, pT, vecs,
                                        h_std, fc1w, fc1b, fc2w, fc2b, out,
                                        l, (l < 3) ? 1 : 0, (l == 3) ? 1 : 0);
    }
}